// Round 11
// baseline (95.993 us; speedup 1.0000x reference)
//
#include <hip/hip_runtime.h>
#include <hip/hip_bf16.h>
#include <hip/hip_fp8.h>
#include <stdint.h>

// TripletLoss (n=4096, d=2048, K=4) — fused MX-fp8 MFMA distance + mining.
//   1. prep: fp32 -> fp8 e4m3 matrix in tile-contiguous permuted layout:
//      within each 128-k tile, granule g = 4*gsel + l4 (l4=(kk>>5)&3,
//      gsel=(kk>>4)&1) at byte g*16; so each lane's 16x16x128 fragment half
//      is one 16B granule and per-instruction granule sets are ALIGNED QUADS
//      {4g..4g+3} -> the R4-bf16-proven 0-conflict read geometry. (R10
//      lesson: stride-2 granule sets conflict pairwise.) Common k-perm of
//      A@A^T is result-invariant. Also sq[] (fp32 exact) + neg_min init.
//   2. gemm: upper-tri 256x256 tiles, R4-proven 8-phase schedule (2 barriers/
//      phase, VMW(4) at ph4/ph8), 512 thr (2Mx4N waves, 128x64/wave),
//      mfma_scale_f32_16x16x128_f8f6f4 (scale=1.0, 2.25x fp8 rate, K=128
//      per instruction), BK=128 (8 iters), 128 KiB dbuf LDS, s_setprio,
//      triangular grid (136 = 8 XCD x 17).
//      Fused epilogue: dist = sqrt(max(sq_i+sq_j-2*dot,1e-12)); row+col mins
//      -> atomicMin; diagonal tiles emit within-identity dist_ap.
//   3. finalize: loss = mean(relu(ap - an + margin)), prec = mean(an > ap)

#define N_ROWS 4096
#define DIM    2048
#define P_IDS  1024
#define NPAIR  (P_IDS * 6)
#define MARGIN 0.3f
#define BK     128          // fp8 k (= bytes) per K-tile row
#define NT     (DIM / BK)   // 16 K-tiles
#define NIT    (NT / 2)     // 8 iterations (2 K-tiles each)
#define NTILE2 16           // 4096 / 256
#define NBLK2  136          // NTILE2*(NTILE2+1)/2 = 8*17

typedef __attribute__((ext_vector_type(4))) float f32x4;
typedef __attribute__((ext_vector_type(4))) int   i32x4;
typedef __attribute__((ext_vector_type(8))) int   i32x8;

__global__ __launch_bounds__(256) void prep_kernel(const float* __restrict__ in,
                                                   uint8_t* __restrict__ f8m,
                                                   float* __restrict__ sq,
                                                   unsigned* __restrict__ neg_bits) {
    const int row = blockIdx.x;
    const int t = threadIdx.x;
    const float4* rp = (const float4*)(in + (size_t)row * DIM);
    float4 v0 = rp[t * 2 + 0];
    float4 v1 = rp[t * 2 + 1];
    float s = v0.x * v0.x + v0.y * v0.y + v0.z * v0.z + v0.w * v0.w
            + v1.x * v1.x + v1.y * v1.y + v1.z * v1.z + v1.w * v1.w;
    float e[8] = {v0.x, v0.y, v0.z, v0.w, v1.x, v1.y, v1.z, v1.w};
    uint64_t pack = 0;
    #pragma unroll
    for (int i = 0; i < 8; ++i) {
        __hip_fp8_e4m3 q(e[i]);                       // OCP e4m3fn, RTNE+sat
        pack |= (uint64_t)(uint8_t)q.__x << (8 * i);
    }
    // Permuted layout: thread t holds k = 8t..8t+7 (kt = t>>4, l4 = (t>>2)&3,
    // gsel = (t>>1)&1, sub = (t&1)*8) -> pos = kt*128 + (4*gsel+l4)*16 + sub.
    const int pos = (t >> 4) * 128 + (4 * ((t >> 1) & 1) + ((t >> 2) & 3)) * 16
                  + (t & 1) * 8;
    *(uint64_t*)(f8m + (size_t)row * DIM + pos) = pack;
    #pragma unroll
    for (int m = 32; m; m >>= 1) s += __shfl_down(s, m, 64);
    __shared__ float red[4];
    if ((t & 63) == 0) red[t >> 6] = s;
    __syncthreads();
    if (t == 0) {
        sq[row] = red[0] + red[1] + red[2] + red[3];
        neg_bits[row] = 0x7F800000u;  // +inf
    }
}

__global__ __launch_bounds__(512, 2) void gemm_kernel(const uint8_t* __restrict__ f8m,
                                                      const float* __restrict__ sq,
                                                      unsigned* __restrict__ neg_bits,
                                                      float* __restrict__ dist_ap) {
    extern __shared__ char smem[];              // 128 KiB dynamic LDS
    uint8_t* const Asb = (uint8_t*)smem;        // [2][256][128] B (64 KiB)
    uint8_t* const Bsb = (uint8_t*)(smem + 65536);
    #define AS(B,R,C) Asb[((B) << 15) + ((R) << 7) + (C)]
    #define BS(B,R,C) Bsb[((B) << 15) + ((R) << 7) + (C)]

    // Bijective XCD-chunk swizzle (136 = 8 * 17).
    const int bid = (blockIdx.x & 7) * (NBLK2 / 8) + (blockIdx.x >> 3);
    int rem = bid, bi = 0;
    while (rem >= NTILE2 - bi) { rem -= NTILE2 - bi; ++bi; }
    const int bj = bi + rem;   // bi <= bj

    const int t = threadIdx.x;
    const int lane = t & 63;
    const int wave = t >> 6;             // 0..7
    const int wr = (wave >> 2) * 128;    // M-half (2 waves)
    const int wc = (wave & 3) * 64;      // N-quarter (4 waves)
    const int lr = lane & 15;
    const int l4 = lane >> 4;            // 0..3 = fragment k-quarter
    f32x4 acc[8][4] = {};

    const int rowA0 = bi * 256;
    const int rowB0 = bj * 256;
    // Staging: stage-lane s -> LDS slot (s&7) of row (s>>3); stored granule
    // gg = (s&7)^(s>>3) (involution), tile-contiguous source col = gg*16.
    const int sr  = lane >> 3;                       // 0..7 row in chunk
    const int gg  = (lane & 7) ^ sr;                 // granule id
    const uint8_t* gA = f8m + (size_t)(rowA0 + sr) * DIM + (gg << 4);
    const uint8_t* gB = f8m + (size_t)(rowB0 + sr) * DIM + (gg << 4);

    // Stage one 128-row half-tile (16 KiB): 2 gloads/wave (chunk = 8 rows).
    #define STAGE_HT(GBASE, LDSB, BUF, H, KT)                                     \
        { _Pragma("unroll")                                                       \
          for (int g = 0; g < 2; ++g) {                                           \
              const int chunk = (H) * 16 + wave * 2 + g;                          \
              __builtin_amdgcn_global_load_lds(                                   \
                  (const __attribute__((address_space(1))) void*)                 \
                      ((GBASE) + (size_t)chunk * 8 * DIM + (KT) * BK),            \
                  (__attribute__((address_space(3))) void*)                       \
                      ((char*)(LDSB) + (BUF) * 32768 + chunk * 1024),             \
                  16, 0, 0);                                                      \
          } }
    #define STAGE_A(BUF, H, KT) STAGE_HT(gA, Asb, BUF, H, KT)
    #define STAGE_B(BUF, H, KT) STAGE_HT(gB, Bsb, BUF, H, KT)

    // Fragment read: 2x ds_read_b128 per 32B fragment (gsel = 0,1). Slot =
    // (4*gsel + l4) ^ (row&7): per-instruction granule set = aligned quad
    // {4g..4g+3} ^ j — the R4-bf16 0-conflict geometry.
    i32x8 af[4], bfr0[2], bfr1[2];
    #define SLOTCOL(GS) (((((GS) * 4 + l4) ^ (lr & 7))) << 4)
    #define LOAD_AF(BUF, MH)                                                      \
        { _Pragma("unroll") for (int m = 0; m < 4; ++m) {                         \
              i32x4 alo = *(const i32x4*)&AS(BUF,                                 \
                  wr + ((MH) * 4 + m) * 16 + lr, SLOTCOL(0));                     \
              i32x4 ahi = *(const i32x4*)&AS(BUF,                                 \
                  wr + ((MH) * 4 + m) * 16 + lr, SLOTCOL(1));                     \
              af[m] = __builtin_shufflevector(alo, ahi, 0,1,2,3,4,5,6,7);         \
          } }
    #define LOAD_BF(DST, BUF, NH)                                                 \
        { _Pragma("unroll") for (int n = 0; n < 2; ++n) {                         \
              i32x4 blo = *(const i32x4*)&BS(BUF,                                 \
                  wc + ((NH) * 2 + n) * 16 + lr, SLOTCOL(0));                     \
              i32x4 bhi = *(const i32x4*)&BS(BUF,                                 \
                  wc + ((NH) * 2 + n) * 16 + lr, SLOTCOL(1));                     \
              DST[n] = __builtin_shufflevector(blo, bhi, 0,1,2,3,4,5,6,7);        \
          } }

    // One K=128 scaled MFMA per (m,n): 8 independent acc targets per call.
    // fmt fp8 = 0 (cbsz/blgp); scale bytes all 0x7F = 1.0 (E8M0).
    #define MFMA_Q(MH, NH, BF)                                                    \
        { __builtin_amdgcn_s_setprio(1);                                          \
          _Pragma("unroll") for (int m = 0; m < 4; ++m)                           \
          _Pragma("unroll") for (int n = 0; n < 2; ++n)                           \
              acc[(MH) * 4 + m][(NH) * 2 + n] =                                   \
                  __builtin_amdgcn_mfma_scale_f32_16x16x128_f8f6f4(               \
                      af[m], BF[n], acc[(MH) * 4 + m][(NH) * 2 + n],              \
                      0, 0, 0, 0x7F7F7F7F, 0, 0x7F7F7F7F);                        \
          __builtin_amdgcn_s_setprio(0); }

    #define BARR() __builtin_amdgcn_s_barrier()
    #define VMW(N) asm volatile("s_waitcnt vmcnt(" #N ")" ::: "memory")

    // Prologue: A(0), B(0) -> buf0; B(1) -> buf1. (A(1) staged in iter0 ph1-2.)
    STAGE_A(0, 0, 0); STAGE_A(0, 1, 0);
    STAGE_B(0, 0, 0); STAGE_B(0, 1, 0);
    STAGE_B(1, 0, 1); STAGE_B(1, 1, 1);
    VMW(0);
    BARR();

    for (int i = 0; i < NIT - 1; ++i) {
        const int t2 = 2 * i;
        // ph1: compute t2 (buf0) quadrant (0,0); stage A(t2+1).h0 -> buf1
        LOAD_AF(0, 0); LOAD_BF(bfr0, 0, 0);
        STAGE_A(1, 0, t2 + 1);
        BARR(); MFMA_Q(0, 0, bfr0); BARR();
        // ph2
        LOAD_BF(bfr1, 0, 1);
        STAGE_A(1, 1, t2 + 1);
        BARR(); MFMA_Q(0, 1, bfr1); BARR();
        // ph3
        LOAD_AF(0, 1);
        STAGE_B(0, 0, t2 + 2);
        BARR(); MFMA_Q(1, 1, bfr1); BARR();
        // ph4: counted drain (A(t+1)+B(t+1) landed; B(t+2) in flight)
        STAGE_B(0, 1, t2 + 2);
        BARR(); MFMA_Q(1, 0, bfr0); VMW(4); BARR();
        // ph5: compute t2+1 (buf1); stage A(t2+2).h0 -> buf0
        LOAD_AF(1, 0); LOAD_BF(bfr0, 1, 0);
        STAGE_A(0, 0, t2 + 2);
        BARR(); MFMA_Q(0, 0, bfr0); BARR();
        // ph6
        LOAD_BF(bfr1, 1, 1);
        STAGE_A(0, 1, t2 + 2);
        BARR(); MFMA_Q(0, 1, bfr1); BARR();
        // ph7
        LOAD_AF(1, 1);
        STAGE_B(1, 0, t2 + 3);
        BARR(); MFMA_Q(1, 1, bfr1); BARR();
        // ph8: counted drain (A(t+2)+B(t+2) landed; B(t+3) in flight)
        STAGE_B(1, 1, t2 + 3);
        BARR(); MFMA_Q(1, 0, bfr0); VMW(4); BARR();
    }
    // Peeled last iteration (t2 = 14): no stages for tiles 16/17.
    {
        LOAD_AF(0, 0); LOAD_BF(bfr0, 0, 0);
        STAGE_A(1, 0, NT - 1);
        BARR(); MFMA_Q(0, 0, bfr0); BARR();
        LOAD_BF(bfr1, 0, 1);
        STAGE_A(1, 1, NT - 1);
        BARR(); MFMA_Q(0, 1, bfr1); BARR();
        LOAD_AF(0, 1);
        BARR(); MFMA_Q(1, 1, bfr1); BARR();
        BARR(); MFMA_Q(1, 0, bfr0); VMW(0); BARR();
        LOAD_AF(1, 0); LOAD_BF(bfr0, 1, 0);
        BARR(); MFMA_Q(0, 0, bfr0); BARR();
        LOAD_BF(bfr1, 1, 1);
        BARR(); MFMA_Q(0, 1, bfr1); BARR();
        LOAD_AF(1, 1);
        BARR(); MFMA_Q(1, 1, bfr1); BARR();
        MFMA_Q(1, 0, bfr0);
    }

    // ---- fused epilogue (C/D layout shape-determined, same as 16x16 bf16) ----
    const bool diag = (bi == bj);
    const int l15 = lane & 15;
    float sqc[4];
    #pragma unroll
    for (int n = 0; n < 4; ++n) sqc[n] = sq[rowB0 + wc + n * 16 + l15];
    float colmin[4] = {INFINITY, INFINITY, INFINITY, INFINITY};

    #pragma unroll
    for (int m = 0; m < 8; ++m) {
        #pragma unroll
        for (int r = 0; r < 4; ++r) {
            const int grow = rowA0 + wr + m * 16 + l4 * 4 + r;
            const float sqr = sq[grow];
            float rmin = INFINITY;
            #pragma unroll
            for (int n = 0; n < 4; ++n) {
                const int gcol = rowB0 + wc + n * 16 + l15;
                const float d2 = sqr + sqc[n] - 2.0f * acc[m][n][r];
                const float d = sqrtf(fmaxf(d2, 1e-12f));
                float cand = d;
                if (diag && ((grow >> 2) == (gcol >> 2))) {
                    if (grow < gcol) {  // within-identity pair (a<b)
                        const int p = grow >> 2;
                        const int a = grow & 3, b = gcol & 3;
                        dist_ap[p * 6 + (a * (7 - a)) / 2 + (b - a - 1)] = d;
                    }
                    cand = INFINITY;  // mask positives from mining
                }
                rmin = fminf(rmin, cand);
                colmin[n] = fminf(colmin[n], cand);
            }
            rmin = fminf(rmin, __shfl_xor(rmin, 1, 64));
            rmin = fminf(rmin, __shfl_xor(rmin, 2, 64));
            rmin = fminf(rmin, __shfl_xor(rmin, 4, 64));
            rmin = fminf(rmin, __shfl_xor(rmin, 8, 64));
            if (l15 == 0) atomicMin(&neg_bits[grow], __float_as_uint(rmin));
        }
    }
    if (!diag) {  // transpose contribution (col mins)
        #pragma unroll
        for (int n = 0; n < 4; ++n) {
            float v = colmin[n];
            v = fminf(v, __shfl_xor(v, 16, 64));
            v = fminf(v, __shfl_xor(v, 32, 64));
            if (l4 == 0)
                atomicMin(&neg_bits[rowB0 + wc + n * 16 + l15], __float_as_uint(v));
        }
    }
}

__global__ __launch_bounds__(256) void finalize_kernel(const unsigned* __restrict__ neg_bits,
                                                       const float* __restrict__ dist_ap,
                                                       float* __restrict__ out) {
    const int t = threadIdx.x;
    float sum = 0.f, cnt = 0.f;
    for (int e = t; e < NPAIR; e += 256) {
        const int p = e / 6;
        const int idx = e - p * 6;
        const int a = (idx < 3) ? 0 : ((idx < 5) ? 1 : 2);  // triu jj for K=4
        const float an = __uint_as_float(neg_bits[p * 4 + a]);
        const float ap = dist_ap[e];
        sum += fmaxf(ap - an + MARGIN, 0.f);
        cnt += (an > ap) ? 1.f : 0.f;
    }
    #pragma unroll
    for (int m = 32; m; m >>= 1) {
        sum += __shfl_down(sum, m, 64);
        cnt += __shfl_down(cnt, m, 64);
    }
    __shared__ float rs[4], rc[4];
    if ((t & 63) == 0) { rs[t >> 6] = sum; rc[t >> 6] = cnt; }
    __syncthreads();
    if (t == 0) {
        out[0] = (rs[0] + rs[1] + rs[2] + rs[3]) / (float)NPAIR;
        out[1] = (rc[0] + rc[1] + rc[2] + rc[3]) / (float)NPAIR;
    }
}

extern "C" void kernel_launch(void* const* d_in, const int* in_sizes, int n_in,
                              void* d_out, int out_size, void* d_ws, size_t ws_size,
                              hipStream_t stream) {
    const float* inputs = (const float*)d_in[0];
    float* out = (float*)d_out;
    char* ws = (char*)d_ws;
    uint8_t* f8m = (uint8_t*)ws;                               // 8 MiB
    float* sq = (float*)(ws + (size_t)N_ROWS * DIM);           // 16 KiB
    unsigned* neg_bits = (unsigned*)((char*)sq + N_ROWS * 4);  // 16 KiB
    float* dist_ap = (float*)((char*)neg_bits + N_ROWS * 4);   // 24 KiB

    prep_kernel<<<N_ROWS, 256, 0, stream>>>(inputs, f8m, sq, neg_bits);
    gemm_kernel<<<NBLK2, 512, 131072, stream>>>(f8m, sq, neg_bits, dist_ap);
    finalize_kernel<<<1, 256, 0, stream>>>(neg_bits, dist_ap, out);
}

// Round 12
// 95.632 us; speedup vs baseline: 1.0038x; 1.0038x over previous
//
#include <hip/hip_runtime.h>
#include <hip/hip_bf16.h>
#include <hip/hip_fp8.h>
#include <stdint.h>

// TripletLoss (n=4096, d=2048, K=4) — fused MX-fp8 MFMA distance + mining.
//   1. prep: fp32 -> fp8 e4m3 in tile-contiguous permuted layout (granule
//      g = 4*gsel + l4 within each 128-k tile) -> aligned-quad 0-conflict
//      ds_read_b128 geometry (R11-verified: SQ_LDS_BANK_CONFLICT = 0).
//   2. gemm: upper-tri 256x256 tiles, MERGED 4-phase iteration (R11 post-
//      mortem: phases are overhead-dominated ~3000cyc vs ~700cyc work; MFMA
//      is only ~8% busy). Each phase: {ds-loads ; both-half STAGE ; BARR ;
//      2 MFMA quadrant bursts ; [VMW(4)] ; BARR}. Invariants preserved vs
//      the proven 8-phase: 2 barriers/segment, >=2 barriers between LDS
//      read-complete and overwrite, identical VMW(4) drain algebra
//      (P2: drains A(t+1) of 8 outstanding; P4: drains B(t+2)+A(t+2) of 12,
//      leaves B(t+3)). mfma_scale_f32_16x16x128_f8f6f4 (scale=1.0), BK=128,
//      512 thr (2Mx4N waves, 128x64/wave), 128 KiB dbuf LDS, s_setprio,
//      triangular grid (136 = 8 XCD x 17). Fragments load directly into
//      i32x8 halves (no shufflevector movs).
//      Fused epilogue: dist = sqrt(max(sq_i+sq_j-2*dot,1e-12)); row+col mins
//      -> atomicMin; diagonal tiles emit within-identity dist_ap.
//   3. finalize: loss = mean(relu(ap - an + margin)), prec = mean(an > ap)

#define N_ROWS 4096
#define DIM    2048
#define P_IDS  1024
#define NPAIR  (P_IDS * 6)
#define MARGIN 0.3f
#define BK     128          // fp8 k (= bytes) per K-tile row
#define NT     (DIM / BK)   // 16 K-tiles
#define NIT    (NT / 2)     // 8 iterations (2 K-tiles each)
#define NTILE2 16           // 4096 / 256
#define NBLK2  136          // NTILE2*(NTILE2+1)/2 = 8*17

typedef __attribute__((ext_vector_type(4))) float f32x4;
typedef __attribute__((ext_vector_type(4))) int   i32x4;
typedef __attribute__((ext_vector_type(8))) int   i32x8;

__global__ __launch_bounds__(256) void prep_kernel(const float* __restrict__ in,
                                                   uint8_t* __restrict__ f8m,
                                                   float* __restrict__ sq,
                                                   unsigned* __restrict__ neg_bits) {
    const int row = blockIdx.x;
    const int t = threadIdx.x;
    const float4* rp = (const float4*)(in + (size_t)row * DIM);
    float4 v0 = rp[t * 2 + 0];
    float4 v1 = rp[t * 2 + 1];
    float s = v0.x * v0.x + v0.y * v0.y + v0.z * v0.z + v0.w * v0.w
            + v1.x * v1.x + v1.y * v1.y + v1.z * v1.z + v1.w * v1.w;
    float e[8] = {v0.x, v0.y, v0.z, v0.w, v1.x, v1.y, v1.z, v1.w};
    uint64_t pack = 0;
    #pragma unroll
    for (int i = 0; i < 8; ++i) {
        __hip_fp8_e4m3 q(e[i]);                       // OCP e4m3fn, RTNE+sat
        pack |= (uint64_t)(uint8_t)q.__x << (8 * i);
    }
    // Permuted layout: thread t holds k = 8t..8t+7 (kt = t>>4, l4 = (t>>2)&3,
    // gsel = (t>>1)&1, sub = (t&1)*8) -> pos = kt*128 + (4*gsel+l4)*16 + sub.
    const int pos = (t >> 4) * 128 + (4 * ((t >> 1) & 1) + ((t >> 2) & 3)) * 16
                  + (t & 1) * 8;
    *(uint64_t*)(f8m + (size_t)row * DIM + pos) = pack;
    #pragma unroll
    for (int m = 32; m; m >>= 1) s += __shfl_down(s, m, 64);
    __shared__ float red[4];
    if ((t & 63) == 0) red[t >> 6] = s;
    __syncthreads();
    if (t == 0) {
        sq[row] = red[0] + red[1] + red[2] + red[3];
        neg_bits[row] = 0x7F800000u;  // +inf
    }
}

__global__ __launch_bounds__(512, 2) void gemm_kernel(const uint8_t* __restrict__ f8m,
                                                      const float* __restrict__ sq,
                                                      unsigned* __restrict__ neg_bits,
                                                      float* __restrict__ dist_ap) {
    extern __shared__ char smem[];              // 128 KiB dynamic LDS
    uint8_t* const Asb = (uint8_t*)smem;        // [2][256][128] B (64 KiB)
    uint8_t* const Bsb = (uint8_t*)(smem + 65536);
    #define AS(B,R,C) Asb[((B) << 15) + ((R) << 7) + (C)]
    #define BS(B,R,C) Bsb[((B) << 15) + ((R) << 7) + (C)]

    // Bijective XCD-chunk swizzle (136 = 8 * 17).
    const int bid = (blockIdx.x & 7) * (NBLK2 / 8) + (blockIdx.x >> 3);
    int rem = bid, bi = 0;
    while (rem >= NTILE2 - bi) { rem -= NTILE2 - bi; ++bi; }
    const int bj = bi + rem;   // bi <= bj

    const int t = threadIdx.x;
    const int lane = t & 63;
    const int wave = t >> 6;             // 0..7
    const int wr = (wave >> 2) * 128;    // M-half (2 waves)
    const int wc = (wave & 3) * 64;      // N-quarter (4 waves)
    const int lr = lane & 15;
    const int l4 = lane >> 4;            // 0..3 = fragment k-quarter
    f32x4 acc[8][4] = {};

    const int rowA0 = bi * 256;
    const int rowB0 = bj * 256;
    // Staging: stage-lane s -> LDS slot (s&7) of row (s>>3); stored granule
    // gg = (s&7)^(s>>3) (involution), tile-contiguous source col = gg*16.
    const int sr  = lane >> 3;                       // 0..7 row in chunk
    const int gg  = (lane & 7) ^ sr;                 // granule id
    const uint8_t* gA = f8m + (size_t)(rowA0 + sr) * DIM + (gg << 4);
    const uint8_t* gB = f8m + (size_t)(rowB0 + sr) * DIM + (gg << 4);

    // Stage one 128-row half-tile (16 KiB): 2 gloads/wave (chunk = 8 rows).
    #define STAGE_HT(GBASE, LDSB, BUF, H, KT)                                     \
        { _Pragma("unroll")                                                       \
          for (int g = 0; g < 2; ++g) {                                           \
              const int chunk = (H) * 16 + wave * 2 + g;                          \
              __builtin_amdgcn_global_load_lds(                                   \
                  (const __attribute__((address_space(1))) void*)                 \
                      ((GBASE) + (size_t)chunk * 8 * DIM + (KT) * BK),            \
                  (__attribute__((address_space(3))) void*)                       \
                      ((char*)(LDSB) + (BUF) * 32768 + chunk * 1024),             \
                  16, 0, 0);                                                      \
          } }
    #define STAGE_A(BUF, H, KT) STAGE_HT(gA, Asb, BUF, H, KT)
    #define STAGE_B(BUF, H, KT) STAGE_HT(gB, Bsb, BUF, H, KT)

    // Fragment read: 2x ds_read_b128 per 32B fragment, written directly into
    // the i32x8's halves (no shufflevector). Slot = (4*gsel + l4) ^ (row&7):
    // per-instruction granule set = aligned quad -> 0 conflicts (R11 ✓).
    i32x8 af[4], bfr0[2], bfr1[2];
    #define SLOTCOL(GS) (((((GS) * 4 + l4) ^ (lr & 7))) << 4)
    #define LOAD_AF(BUF, MH)                                                      \
        { _Pragma("unroll") for (int m = 0; m < 4; ++m) {                         \
              i32x4* ph = (i32x4*)&af[m];                                         \
              ph[0] = *(const i32x4*)&AS(BUF,                                     \
                  wr + ((MH) * 4 + m) * 16 + lr, SLOTCOL(0));                     \
              ph[1] = *(const i32x4*)&AS(BUF,                                     \
                  wr + ((MH) * 4 + m) * 16 + lr, SLOTCOL(1));                     \
          } }
    #define LOAD_BF(DST, BUF, NH)                                                 \
        { _Pragma("unroll") for (int n = 0; n < 2; ++n) {                         \
              i32x4* ph = (i32x4*)&DST[n];                                        \
              ph[0] = *(const i32x4*)&BS(BUF,                                     \
                  wc + ((NH) * 2 + n) * 16 + lr, SLOTCOL(0));                     \
              ph[1] = *(const i32x4*)&BS(BUF,                                     \
                  wc + ((NH) * 2 + n) * 16 + lr, SLOTCOL(1));                     \
          } }

    // One K=128 scaled MFMA per (m,n): 8 independent acc targets per call.
    // fmt fp8 = 0 (cbsz/blgp); scale bytes all 0x7F = 1.0 (E8M0).
    #define MFMA_Q(MH, NH, BF)                                                    \
        { __builtin_amdgcn_s_setprio(1);                                          \
          _Pragma("unroll") for (int m = 0; m < 4; ++m)                           \
          _Pragma("unroll") for (int n = 0; n < 2; ++n)                           \
              acc[(MH) * 4 + m][(NH) * 2 + n] =                                   \
                  __builtin_amdgcn_mfma_scale_f32_16x16x128_f8f6f4(               \
                      af[m], BF[n], acc[(MH) * 4 + m][(NH) * 2 + n],              \
                      0, 0, 0, 0x7F7F7F7F, 0, 0x7F7F7F7F);                        \
          __builtin_amdgcn_s_setprio(0); }

    #define BARR() __builtin_amdgcn_s_barrier()
    #define VMW(N) asm volatile("s_waitcnt vmcnt(" #N ")" ::: "memory")

    // Prologue: A(0), B(0) -> buf0; B(1) -> buf1. (A(1) staged in P1.)
    STAGE_A(0, 0, 0); STAGE_A(0, 1, 0);
    STAGE_B(0, 0, 0); STAGE_B(0, 1, 0);
    STAGE_B(1, 0, 1); STAGE_B(1, 1, 1);
    VMW(0);
    BARR();

    // Merged 4-phase iteration (2 K-tiles). Barrier pairing and VMW(4)
    // drain algebra identical to the proven 8-phase schedule.
    for (int i = 0; i < NIT - 1; ++i) {
        const int t2 = 2 * i;
        // P1: frags(t2, MH0 + both B halves); stage A(t2+1) both halves
        LOAD_AF(0, 0); LOAD_BF(bfr0, 0, 0); LOAD_BF(bfr1, 0, 1);
        STAGE_A(1, 0, t2 + 1); STAGE_A(1, 1, t2 + 1);
        BARR(); MFMA_Q(0, 0, bfr0); MFMA_Q(0, 1, bfr1); BARR();
        // P2: frags(t2, MH1); stage B(t2+2); drain A(t2+1) (8 out -> 4)
        LOAD_AF(0, 1);
        STAGE_B(0, 0, t2 + 2); STAGE_B(0, 1, t2 + 2);
        BARR(); MFMA_Q(1, 1, bfr1); MFMA_Q(1, 0, bfr0); VMW(4); BARR();
        // P3: frags(t2+1); stage A(t2+2)
        LOAD_AF(1, 0); LOAD_BF(bfr0, 1, 0); LOAD_BF(bfr1, 1, 1);
        STAGE_A(0, 0, t2 + 2); STAGE_A(0, 1, t2 + 2);
        BARR(); MFMA_Q(0, 0, bfr0); MFMA_Q(0, 1, bfr1); BARR();
        // P4: stage B(t2+3); drain B(t2+2)+A(t2+2) (12 out -> 4)
        LOAD_AF(1, 1);
        STAGE_B(1, 0, t2 + 3); STAGE_B(1, 1, t2 + 3);
        BARR(); MFMA_Q(1, 1, bfr1); MFMA_Q(1, 0, bfr0); VMW(4); BARR();
    }
    // Peeled last iteration (t2 = 14): no stages for tiles 16/17.
    {
        LOAD_AF(0, 0); LOAD_BF(bfr0, 0, 0); LOAD_BF(bfr1, 0, 1);
        STAGE_A(1, 0, NT - 1); STAGE_A(1, 1, NT - 1);
        BARR(); MFMA_Q(0, 0, bfr0); MFMA_Q(0, 1, bfr1); BARR();
        LOAD_AF(0, 1);
        BARR(); MFMA_Q(1, 1, bfr1); MFMA_Q(1, 0, bfr0); VMW(0); BARR();
        LOAD_AF(1, 0); LOAD_BF(bfr0, 1, 0); LOAD_BF(bfr1, 1, 1);
        BARR(); MFMA_Q(0, 0, bfr0); MFMA_Q(0, 1, bfr1); BARR();
        LOAD_AF(1, 1);
        BARR(); MFMA_Q(1, 1, bfr1); MFMA_Q(1, 0, bfr0);
    }

    // ---- fused epilogue (C/D layout shape-determined, same as 16x16 bf16) ----
    const bool diag = (bi == bj);
    const int l15 = lane & 15;
    float sqc[4];
    #pragma unroll
    for (int n = 0; n < 4; ++n) sqc[n] = sq[rowB0 + wc + n * 16 + l15];
    float colmin[4] = {INFINITY, INFINITY, INFINITY, INFINITY};

    #pragma unroll
    for (int m = 0; m < 8; ++m) {
        #pragma unroll
        for (int r = 0; r < 4; ++r) {
            const int grow = rowA0 + wr + m * 16 + l4 * 4 + r;
            const float sqr = sq[grow];
            float rmin = INFINITY;
            #pragma unroll
            for (int n = 0; n < 4; ++n) {
                const int gcol = rowB0 + wc + n * 16 + l15;
                const float d2 = sqr + sqc[n] - 2.0f * acc[m][n][r];
                const float d = sqrtf(fmaxf(d2, 1e-12f));
                float cand = d;
                if (diag && ((grow >> 2) == (gcol >> 2))) {
                    if (grow < gcol) {  // within-identity pair (a<b)
                        const int p = grow >> 2;
                        const int a = grow & 3, b = gcol & 3;
                        dist_ap[p * 6 + (a * (7 - a)) / 2 + (b - a - 1)] = d;
                    }
                    cand = INFINITY;  // mask positives from mining
                }
                rmin = fminf(rmin, cand);
                colmin[n] = fminf(colmin[n], cand);
            }
            rmin = fminf(rmin, __shfl_xor(rmin, 1, 64));
            rmin = fminf(rmin, __shfl_xor(rmin, 2, 64));
            rmin = fminf(rmin, __shfl_xor(rmin, 4, 64));
            rmin = fminf(rmin, __shfl_xor(rmin, 8, 64));
            if (l15 == 0) atomicMin(&neg_bits[grow], __float_as_uint(rmin));
        }
    }
    if (!diag) {  // transpose contribution (col mins)
        #pragma unroll
        for (int n = 0; n < 4; ++n) {
            float v = colmin[n];
            v = fminf(v, __shfl_xor(v, 16, 64));
            v = fminf(v, __shfl_xor(v, 32, 64));
            if (l4 == 0)
                atomicMin(&neg_bits[rowB0 + wc + n * 16 + l15], __float_as_uint(v));
        }
    }
}

__global__ __launch_bounds__(256) void finalize_kernel(const unsigned* __restrict__ neg_bits,
                                                       const float* __restrict__ dist_ap,
                                                       float* __restrict__ out) {
    const int t = threadIdx.x;
    float sum = 0.f, cnt = 0.f;
    for (int e = t; e < NPAIR; e += 256) {
        const int p = e / 6;
        const int idx = e - p * 6;
        const int a = (idx < 3) ? 0 : ((idx < 5) ? 1 : 2);  // triu jj for K=4
        const float an = __uint_as_float(neg_bits[p * 4 + a]);
        const float ap = dist_ap[e];
        sum += fmaxf(ap - an + MARGIN, 0.f);
        cnt += (an > ap) ? 1.f : 0.f;
    }
    #pragma unroll
    for (int m = 32; m; m >>= 1) {
        sum += __shfl_down(sum, m, 64);
        cnt += __shfl_down(cnt, m, 64);
    }
    __shared__ float rs[4], rc[4];
    if ((t & 63) == 0) { rs[t >> 6] = sum; rc[t >> 6] = cnt; }
    __syncthreads();
    if (t == 0) {
        out[0] = (rs[0] + rs[1] + rs[2] + rs[3]) / (float)NPAIR;
        out[1] = (rc[0] + rc[1] + rc[2] + rc[3]) / (float)NPAIR;
    }
}

extern "C" void kernel_launch(void* const* d_in, const int* in_sizes, int n_in,
                              void* d_out, int out_size, void* d_ws, size_t ws_size,
                              hipStream_t stream) {
    const float* inputs = (const float*)d_in[0];
    float* out = (float*)d_out;
    char* ws = (char*)d_ws;
    uint8_t* f8m = (uint8_t*)ws;                               // 8 MiB
    float* sq = (float*)(ws + (size_t)N_ROWS * DIM);           // 16 KiB
    unsigned* neg_bits = (unsigned*)((char*)sq + N_ROWS * 4);  // 16 KiB
    float* dist_ap = (float*)((char*)neg_bits + N_ROWS * 4);   // 24 KiB

    prep_kernel<<<N_ROWS, 256, 0, stream>>>(inputs, f8m, sq, neg_bits);
    gemm_kernel<<<NBLK2, 512, 131072, stream>>>(f8m, sq, neg_bits, dist_ap);
    finalize_kernel<<<1, 256, 0, stream>>>(neg_bits, dist_ap, out);
}

// Round 13
// 83.180 us; speedup vs baseline: 1.1540x; 1.1497x over previous
//
#include <hip/hip_runtime.h>
#include <hip/hip_bf16.h>
#include <hip/hip_fp8.h>
#include <stdint.h>

// TripletLoss (n=4096, d=2048, K=4) — fused fp8-MFMA distance + mining.
//   1. prep: fp32 -> fp8 e4m3 in tile-contiguous ALIGNED-QUAD permuted layout:
//      within each 128-k tile, granule g = 4*kp + l4 holds the 16B that lane
//      quarter l4 needs for MFMA k-pair kp (halves ks=2kp, 2kp+1). Common
//      k-permutation of A@A^T is result-invariant. sq[] fp32-exact; neg_min
//      init.
//   2. gemm: upper-tri 256x256 tiles, R4/R10-proven 8-phase schedule (2
//      barriers/phase, VMW(4) at ph4/ph8), 512 thr (2Mx4N waves, 128x64/
//      wave), MFMA 16x16x32_fp8_fp8 (bf16 rate, half LDS bytes), BK=128
//      (8 iters), 128 KiB dbuf LDS. Fragment reads: one ds_read_b128 per
//      k-pair into long2v (STATIC component indexing — R12 lesson: pointer-
//      cast half-writes into i32x8 forced scratch, 35 MB/dispatch HBM).
//      Read slot = (4*kp + l4) ^ (row&7): aligned-quad granule sets = the
//      R4-bf16 0-conflict geometry (R10's stride-2 sets cost 1.67e6).
//      Fused epilogue: dist = sqrt(max(sq_i+sq_j-2*dot,1e-12)); row+col mins
//      -> atomicMin; diagonal tiles emit within-identity dist_ap.
//   3. finalize: loss = mean(relu(ap - an + margin)), prec = mean(an > ap)

#define N_ROWS 4096
#define DIM    2048
#define P_IDS  1024
#define NPAIR  (P_IDS * 6)
#define MARGIN 0.3f
#define BK     128          // fp8 k (= bytes) per K-tile row
#define NT     (DIM / BK)   // 16 K-tiles
#define NIT    (NT / 2)     // 8 iterations (2 K-tiles each)
#define NTILE2 16           // 4096 / 256
#define NBLK2  136          // NTILE2*(NTILE2+1)/2 = 8*17

typedef __attribute__((ext_vector_type(4))) float f32x4;
typedef __attribute__((ext_vector_type(2))) long long2v;

__global__ __launch_bounds__(256) void prep_kernel(const float* __restrict__ in,
                                                   uint8_t* __restrict__ f8m,
                                                   float* __restrict__ sq,
                                                   unsigned* __restrict__ neg_bits) {
    const int row = blockIdx.x;
    const int t = threadIdx.x;
    const float4* rp = (const float4*)(in + (size_t)row * DIM);
    float4 v0 = rp[t * 2 + 0];
    float4 v1 = rp[t * 2 + 1];
    float s = v0.x * v0.x + v0.y * v0.y + v0.z * v0.z + v0.w * v0.w
            + v1.x * v1.x + v1.y * v1.y + v1.z * v1.z + v1.w * v1.w;
    float e[8] = {v0.x, v0.y, v0.z, v0.w, v1.x, v1.y, v1.z, v1.w};
    uint64_t pack = 0;
    #pragma unroll
    for (int i = 0; i < 8; ++i) {
        __hip_fp8_e4m3 q(e[i]);                       // OCP e4m3fn, RTNE+sat
        pack |= (uint64_t)(uint8_t)q.__x << (8 * i);
    }
    // Aligned-quad layout: thread t holds k = 8t..8t+7 (tile = t>>4,
    // kp = (t>>3)&1, half = (t>>2)&1, l4 = t&3) ->
    // pos = tile*128 + (4*kp + l4)*16 + half*8.
    const int pos = (t >> 4) * 128 + ((((t >> 3) & 1) * 4) + (t & 3)) * 16
                  + ((t >> 2) & 1) * 8;
    *(uint64_t*)(f8m + (size_t)row * DIM + pos) = pack;
    #pragma unroll
    for (int m = 32; m; m >>= 1) s += __shfl_down(s, m, 64);
    __shared__ float red[4];
    if ((t & 63) == 0) red[t >> 6] = s;
    __syncthreads();
    if (t == 0) {
        sq[row] = red[0] + red[1] + red[2] + red[3];
        neg_bits[row] = 0x7F800000u;  // +inf
    }
}

__global__ __launch_bounds__(512, 2) void gemm_kernel(const uint8_t* __restrict__ f8m,
                                                      const float* __restrict__ sq,
                                                      unsigned* __restrict__ neg_bits,
                                                      float* __restrict__ dist_ap) {
    extern __shared__ char smem[];              // 128 KiB dynamic LDS
    uint8_t* const Asb = (uint8_t*)smem;        // [2][256][128] B (64 KiB)
    uint8_t* const Bsb = (uint8_t*)(smem + 65536);
    #define AS(B,R,C) Asb[((B) << 15) + ((R) << 7) + (C)]
    #define BS(B,R,C) Bsb[((B) << 15) + ((R) << 7) + (C)]

    // Bijective XCD-chunk swizzle (136 = 8 * 17).
    const int bid = (blockIdx.x & 7) * (NBLK2 / 8) + (blockIdx.x >> 3);
    int rem = bid, bi = 0;
    while (rem >= NTILE2 - bi) { rem -= NTILE2 - bi; ++bi; }
    const int bj = bi + rem;   // bi <= bj

    const int t = threadIdx.x;
    const int lane = t & 63;
    const int wave = t >> 6;             // 0..7
    const int wr = (wave >> 2) * 128;    // M-half (2 waves)
    const int wc = (wave & 3) * 64;      // N-quarter (4 waves)
    const int lr = lane & 15;
    const int l4 = lane >> 4;            // 0..3 = fragment k-quarter
    f32x4 acc[8][4] = {};

    const int rowA0 = bi * 256;
    const int rowB0 = bj * 256;
    // Staging: stage-lane s -> LDS slot (s&7) of row (s>>3); stored granule
    // gg = (s&7)^(s>>3) (involution), tile-contiguous source col = gg*16.
    const int sr  = lane >> 3;                       // 0..7 row in chunk
    const int gg  = (lane & 7) ^ sr;                 // granule id (4*kp+l4)
    const uint8_t* gA = f8m + (size_t)(rowA0 + sr) * DIM + (gg << 4);
    const uint8_t* gB = f8m + (size_t)(rowB0 + sr) * DIM + (gg << 4);

    // Stage one 128-row half-tile (16 KiB): 2 gloads/wave (chunk = 8 rows).
    #define STAGE_HT(GBASE, LDSB, BUF, H, KT)                                     \
        { _Pragma("unroll")                                                       \
          for (int g = 0; g < 2; ++g) {                                           \
              const int chunk = (H) * 16 + wave * 2 + g;                          \
              __builtin_amdgcn_global_load_lds(                                   \
                  (const __attribute__((address_space(1))) void*)                 \
                      ((GBASE) + (size_t)chunk * 8 * DIM + (KT) * BK),            \
                  (__attribute__((address_space(3))) void*)                       \
                      ((char*)(LDSB) + (BUF) * 32768 + chunk * 1024),             \
                  16, 0, 0);                                                      \
          } }
    #define STAGE_A(BUF, H, KT) STAGE_HT(gA, Asb, BUF, H, KT)
    #define STAGE_B(BUF, H, KT) STAGE_HT(gB, Bsb, BUF, H, KT)

    // Fragment read: ONE ds_read_b128 per k-pair kp (halves = MFMA steps
    // ks = 2kp, 2kp+1; static component index). Slot = (4*kp + l4) ^
    // (row&7): aligned-quad granule sets -> 2 lanes/bank = free (R4 geom).
    long2v afp[8], bfp0[4], bfp1[4];
    #define SLOTCOL(KP) (((((KP) * 4 + l4) ^ (lr & 7))) << 4)
    #define LOAD_AF(BUF, MH)                                                      \
        { _Pragma("unroll") for (int m = 0; m < 4; ++m)                           \
          _Pragma("unroll") for (int kp = 0; kp < 2; ++kp)                        \
              afp[m * 2 + kp] = *(const long2v*)&AS(BUF,                          \
                  wr + ((MH) * 4 + m) * 16 + lr, SLOTCOL(kp)); }
    #define LOAD_BF(DST, BUF, NH)                                                 \
        { _Pragma("unroll") for (int n = 0; n < 2; ++n)                           \
          _Pragma("unroll") for (int kp = 0; kp < 2; ++kp)                        \
              DST[n * 2 + kp] = *(const long2v*)&BS(BUF,                          \
                  wc + ((NH) * 2 + n) * 16 + lr, SLOTCOL(kp)); }

    // ks OUTER: 8 independent MFMAs between reuse of the same acc register.
    #define MFMA_Q(MH, NH, BF)                                                    \
        { __builtin_amdgcn_s_setprio(1);                                          \
          _Pragma("unroll") for (int ks = 0; ks < 4; ++ks)                        \
          _Pragma("unroll") for (int m = 0; m < 4; ++m)                           \
          _Pragma("unroll") for (int n = 0; n < 2; ++n)                           \
              acc[(MH) * 4 + m][(NH) * 2 + n] =                                   \
                  __builtin_amdgcn_mfma_f32_16x16x32_fp8_fp8(                     \
                      afp[m * 2 + (ks >> 1)][ks & 1],                             \
                      BF[n * 2 + (ks >> 1)][ks & 1],                              \
                      acc[(MH) * 4 + m][(NH) * 2 + n], 0, 0, 0);                  \
          __builtin_amdgcn_s_setprio(0); }

    #define BARR() __builtin_amdgcn_s_barrier()
    #define VMW(N) asm volatile("s_waitcnt vmcnt(" #N ")" ::: "memory")

    // Prologue: A(0), B(0) -> buf0; B(1) -> buf1. (A(1) staged in iter0 ph1-2.)
    STAGE_A(0, 0, 0); STAGE_A(0, 1, 0);
    STAGE_B(0, 0, 0); STAGE_B(0, 1, 0);
    STAGE_B(1, 0, 1); STAGE_B(1, 1, 1);
    VMW(0);
    BARR();

    for (int i = 0; i < NIT - 1; ++i) {
        const int t2 = 2 * i;
        // ph1: compute t2 (buf0) quadrant (0,0); stage A(t2+1).h0 -> buf1
        LOAD_AF(0, 0); LOAD_BF(bfp0, 0, 0);
        STAGE_A(1, 0, t2 + 1);
        BARR(); MFMA_Q(0, 0, bfp0); BARR();
        // ph2
        LOAD_BF(bfp1, 0, 1);
        STAGE_A(1, 1, t2 + 1);
        BARR(); MFMA_Q(0, 1, bfp1); BARR();
        // ph3
        LOAD_AF(0, 1);
        STAGE_B(0, 0, t2 + 2);
        BARR(); MFMA_Q(1, 1, bfp1); BARR();
        // ph4: counted drain (A(t+1)+B(t+1) landed; B(t+2) in flight)
        STAGE_B(0, 1, t2 + 2);
        BARR(); MFMA_Q(1, 0, bfp0); VMW(4); BARR();
        // ph5: compute t2+1 (buf1); stage A(t2+2).h0 -> buf0
        LOAD_AF(1, 0); LOAD_BF(bfp0, 1, 0);
        STAGE_A(0, 0, t2 + 2);
        BARR(); MFMA_Q(0, 0, bfp0); BARR();
        // ph6
        LOAD_BF(bfp1, 1, 1);
        STAGE_A(0, 1, t2 + 2);
        BARR(); MFMA_Q(0, 1, bfp1); BARR();
        // ph7
        LOAD_AF(1, 1);
        STAGE_B(1, 0, t2 + 3);
        BARR(); MFMA_Q(1, 1, bfp1); BARR();
        // ph8: counted drain (A(t+2)+B(t+2) landed; B(t+3) in flight)
        STAGE_B(1, 1, t2 + 3);
        BARR(); MFMA_Q(1, 0, bfp0); VMW(4); BARR();
    }
    // Peeled last iteration (t2 = 14): no stages for tiles 16/17.
    {
        LOAD_AF(0, 0); LOAD_BF(bfp0, 0, 0);
        STAGE_A(1, 0, NT - 1);
        BARR(); MFMA_Q(0, 0, bfp0); BARR();
        LOAD_BF(bfp1, 0, 1);
        STAGE_A(1, 1, NT - 1);
        BARR(); MFMA_Q(0, 1, bfp1); BARR();
        LOAD_AF(0, 1);
        BARR(); MFMA_Q(1, 1, bfp1); BARR();
        BARR(); MFMA_Q(1, 0, bfp0); VMW(0); BARR();
        LOAD_AF(1, 0); LOAD_BF(bfp0, 1, 0);
        BARR(); MFMA_Q(0, 0, bfp0); BARR();
        LOAD_BF(bfp1, 1, 1);
        BARR(); MFMA_Q(0, 1, bfp1); BARR();
        LOAD_AF(1, 1);
        BARR(); MFMA_Q(1, 1, bfp1); BARR();
        MFMA_Q(1, 0, bfp0);
    }

    // ---- fused epilogue (C/D layout dtype-independent, same as bf16) ----
    const bool diag = (bi == bj);
    const int l15 = lane & 15;
    float sqc[4];
    #pragma unroll
    for (int n = 0; n < 4; ++n) sqc[n] = sq[rowB0 + wc + n * 16 + l15];
    float colmin[4] = {INFINITY, INFINITY, INFINITY, INFINITY};

    #pragma unroll
    for (int m = 0; m < 8; ++m) {
        #pragma unroll
        for (int r = 0; r < 4; ++r) {
            const int grow = rowA0 + wr + m * 16 + l4 * 4 + r;
            const float sqr = sq[grow];
            float rmin = INFINITY;
            #pragma unroll
            for (int n = 0; n < 4; ++n) {
                const int gcol = rowB0 + wc + n * 16 + l15;
                const float d2 = sqr + sqc[n] - 2.0f * acc[m][n][r];
                const float d = sqrtf(fmaxf(d2, 1e-12f));
                float cand = d;
                if (diag && ((grow >> 2) == (gcol >> 2))) {
                    if (grow < gcol) {  // within-identity pair (a<b)
                        const int p = grow >> 2;
                        const int a = grow & 3, b = gcol & 3;
                        dist_ap[p * 6 + (a * (7 - a)) / 2 + (b - a - 1)] = d;
                    }
                    cand = INFINITY;  // mask positives from mining
                }
                rmin = fminf(rmin, cand);
                colmin[n] = fminf(colmin[n], cand);
            }
            rmin = fminf(rmin, __shfl_xor(rmin, 1, 64));
            rmin = fminf(rmin, __shfl_xor(rmin, 2, 64));
            rmin = fminf(rmin, __shfl_xor(rmin, 4, 64));
            rmin = fminf(rmin, __shfl_xor(rmin, 8, 64));
            if (l15 == 0) atomicMin(&neg_bits[grow], __float_as_uint(rmin));
        }
    }
    if (!diag) {  // transpose contribution (col mins)
        #pragma unroll
        for (int n = 0; n < 4; ++n) {
            float v = colmin[n];
            v = fminf(v, __shfl_xor(v, 16, 64));
            v = fminf(v, __shfl_xor(v, 32, 64));
            if (l4 == 0)
                atomicMin(&neg_bits[rowB0 + wc + n * 16 + l15], __float_as_uint(v));
        }
    }
}

__global__ __launch_bounds__(256) void finalize_kernel(const unsigned* __restrict__ neg_bits,
                                                       const float* __restrict__ dist_ap,
                                                       float* __restrict__ out) {
    const int t = threadIdx.x;
    float sum = 0.f, cnt = 0.f;
    for (int e = t; e < NPAIR; e += 256) {
        const int p = e / 6;
        const int idx = e - p * 6;
        const int a = (idx < 3) ? 0 : ((idx < 5) ? 1 : 2);  // triu jj for K=4
        const float an = __uint_as_float(neg_bits[p * 4 + a]);
        const float ap = dist_ap[e];
        sum += fmaxf(ap - an + MARGIN, 0.f);
        cnt += (an > ap) ? 1.f : 0.f;
    }
    #pragma unroll
    for (int m = 32; m; m >>= 1) {
        sum += __shfl_down(sum, m, 64);
        cnt += __shfl_down(cnt, m, 64);
    }
    __shared__ float rs[4], rc[4];
    if ((t & 63) == 0) { rs[t >> 6] = sum; rc[t >> 6] = cnt; }
    __syncthreads();
    if (t == 0) {
        out[0] = (rs[0] + rs[1] + rs[2] + rs[3]) / (float)NPAIR;
        out[1] = (rc[0] + rc[1] + rc[2] + rc[3]) / (float)NPAIR;
    }
}

extern "C" void kernel_launch(void* const* d_in, const int* in_sizes, int n_in,
                              void* d_out, int out_size, void* d_ws, size_t ws_size,
                              hipStream_t stream) {
    const float* inputs = (const float*)d_in[0];
    float* out = (float*)d_out;
    char* ws = (char*)d_ws;
    uint8_t* f8m = (uint8_t*)ws;                               // 8 MiB
    float* sq = (float*)(ws + (size_t)N_ROWS * DIM);           // 16 KiB
    unsigned* neg_bits = (unsigned*)((char*)sq + N_ROWS * 4);  // 16 KiB
    float* dist_ap = (float*)((char*)neg_bits + N_ROWS * 4);   // 24 KiB

    prep_kernel<<<N_ROWS, 256, 0, stream>>>(inputs, f8m, sq, neg_bits);
    gemm_kernel<<<NBLK2, 512, 131072, stream>>>(f8m, sq, neg_bits, dist_ap);
    finalize_kernel<<<1, 256, 0, stream>>>(neg_bits, dist_ap, out);
}